// Round 16
// baseline (375.854 us; speedup 1.0000x reference)
//
#include <hip/hip_runtime.h>

#define D 512
#define NH 8
#define DH 64
#define CCTX 64
#define LN_EPS 1e-5f
#define NCHAIN 128          // blocks running the chain
#define FROWS  25           // rows per final tile (50KB LDS)
#define NFB    768          // final blocks: exactly 3/CU on 256 CUs (LDS-bound)

// workspace float offsets
#define WS_T      0        // 8
#define WS_M      512      // 4096
#define WS_CTX    5120     // 64*512
#define WS_CBAR   40960    // 4096
#define WS_O      45056    // 512
#define WS_OUT1   45568    // 512
#define WS_V      46080    // 512
#define WS_ATTN2  46592    // 512
#define WS_FLAGS  47104    // 128 unsigned (chain barrier flags)
#define WS_FLAGS2 47232    // 768 unsigned (final-phase barrier flags)

typedef float f4v __attribute__((ext_vector_type(4)));

__device__ __forceinline__ float waveReduceSum(float v) {
#pragma unroll
    for (int off = 32; off > 0; off >>= 1) v += __shfl_xor(v, off);
    return v;
}

// Chain barrier (128 blocks): release own flag, RELAXED polls, one acquire
// fence on exit (r7-validated).
__device__ __forceinline__ void barFlags(unsigned* flags, unsigned phase) {
    __syncthreads();
    if (threadIdx.x == 0)
        __hip_atomic_store(&flags[blockIdx.x], phase, __ATOMIC_RELEASE,
                           __HIP_MEMORY_SCOPE_AGENT);
    if (threadIdx.x < 64) {
        while (true) {
            unsigned f0 = __hip_atomic_load(&flags[threadIdx.x],
                                            __ATOMIC_RELAXED, __HIP_MEMORY_SCOPE_AGENT);
            unsigned f1 = __hip_atomic_load(&flags[64 + threadIdx.x],
                                            __ATOMIC_RELAXED, __HIP_MEMORY_SCOPE_AGENT);
            if (__all(f0 >= phase && f1 >= phase)) break;
            __builtin_amdgcn_s_sleep(2);
        }
        __builtin_amdgcn_fence(__ATOMIC_ACQUIRE, "agent");
    }
    __syncthreads();
}

// Final-phase barrier (768 blocks): TIMING-ONLY. Release own flag (orders my
// memory ops before the flag), relaxed polls, NO exit acquire fence — after
// the barrier blocks touch only immutable H and their own LDS, so no
// coherence actions are needed and the barrier generates zero invalidation
// traffic.
__device__ __forceinline__ void barFinal(unsigned* f2, unsigned phase) {
    __syncthreads();
    if (threadIdx.x == 0)
        __hip_atomic_store(&f2[blockIdx.x], phase, __ATOMIC_RELEASE,
                           __HIP_MEMORY_SCOPE_AGENT);
    if (threadIdx.x < 64) {
        while (true) {
            bool ok = true;
#pragma unroll
            for (int k = 0; k < NFB / 64; ++k) {
                unsigned v = __hip_atomic_load(&f2[threadIdx.x + k * 64],
                                               __ATOMIC_RELAXED, __HIP_MEMORY_SCOPE_AGENT);
                ok &= (v >= phase);
            }
            if (__all(ok)) break;
            __builtin_amdgcn_s_sleep(1);
        }
    }
    __syncthreads();
}

__global__ __launch_bounds__(1024) void k_init(unsigned* flags) {
    if (threadIdx.x < 128) flags[threadIdx.x] = 0u;
    unsigned* f2 = flags + (WS_FLAGS2 - WS_FLAGS);
    if (threadIdx.x < NFB) f2[threadIdx.x] = 0u;
}

// wave-per-row matvec: y[r] = W[r,:] . x(+head offset) + b[r]
__device__ __forceinline__ void matvec_rows(
    const float* __restrict__ W, const float* __restrict__ x,
    const float* __restrict__ b, float* __restrict__ y, int headStride)
{
    int wib = threadIdx.x >> 6, lane = threadIdx.x & 63;
    int r = blockIdx.x * 4 + wib;                    // 0..511
    const float* xr = x + (r >> 6) * headStride;
    const float* Wr = W + (size_t)r * D;
    float4 w0 = *(const float4*)(Wr + lane * 4);
    float4 w1 = *(const float4*)(Wr + 256 + lane * 4);
    float4 x0 = *(const float4*)(xr + lane * 4);
    float4 x1 = *(const float4*)(xr + 256 + lane * 4);
    float s = w0.x*x0.x + w0.y*x0.y + w0.z*x0.z + w0.w*x0.w
            + w1.x*x1.x + w1.y*x1.y + w1.z*x1.z + w1.w*x1.w;
    s = waveReduceSum(s);
    if (lane == 0) y[r] = s + b[r];
}

// The small chain ALONE: 128 blocks x 256 threads, 5 barriers (R8 structure).
__global__ __launch_bounds__(256) void k_chain(
    const float* __restrict__ Hm,   const float* __restrict__ path,
    const float* __restrict__ Win1, const float* __restrict__ bin1,
    const float* __restrict__ Wout1,const float* __restrict__ bout1,
    const float* __restrict__ Win2, const float* __restrict__ bin2,
    const float* __restrict__ Wout2,const float* __restrict__ bout2,
    const float* __restrict__ ln1g, const float* __restrict__ ln1b,
    const int* __restrict__ ids,    float* __restrict__ ws)
{
    __shared__ __align__(16) float smem[532];
    unsigned* flags = (unsigned*)(ws + WS_FLAGS);
    const int B = blockIdx.x, tid = threadIdx.x;
    const int wib = tid >> 6, lane = tid & 63;

    // ---- P0: gather ctx (blocks 0..63) ; qh+m+t per half-head (blocks 64..79) ----
    if (B < 64) {
        if (tid < 128) {
            int id = ids[B];
            float4 v = *(const float4*)(Hm + (size_t)id * D + tid * 4);
            *(float4*)(ws + WS_CTX + B * D + tid * 4) = v;
        }
    } else if (B < 80) {
        int bm = B - 64;                 // 0..15
        int h = bm >> 1, half = bm & 1;
        float* qh_lds = smem;            // 64 floats: qh for head h
        {
            int rr = tid >> 2, p = tid & 3;
            const float* wrow = Win1 + (size_t)(h * DH + rr) * D + p * 128;
            const float* xrow = path + p * 128;
            float s = 0.f;
#pragma unroll 8
            for (int k = 0; k < 32; ++k) {
                float4 a = *(const float4*)(wrow + k * 4);
                float4 c = *(const float4*)(xrow + k * 4);
                s += a.x*c.x + a.y*c.y + a.z*c.z + a.w*c.w;
            }
            s += __shfl_xor(s, 1);
            s += __shfl_xor(s, 2);
            if (p == 0) qh_lds[rr] = s + bin1[h * DH + rr];
        }
        __syncthreads();
        {
            int c = half * 256 + tid;
            const float* Wk = Win1 + (size_t)D * D;
            float acc = 0.f;
#pragma unroll 8
            for (int d = 0; d < DH; ++d)
                acc += Wk[(size_t)(h * DH + d) * D + c] * qh_lds[d];
            ws[WS_M + h * D + c] = acc;
        }
        if (half == 0 && tid == 0) {
            float tt = 0.f;
            for (int d = 0; d < DH; ++d) tt += bin1[D + h * DH + d] * qh_lds[d];
            ws[WS_T + h] = tt;
        }
    }
    barFlags(flags, 1);

    // ---- P1: blocks 0..7 (one per head) — scores -> softmax -> cbar_h ----
    if (B < NH) {
        const int h = B;
        float* s_lds = smem;          // 64 scores
        float* w_lds = smem + 64;     // 64 weights
        {
            int j = tid >> 2, p = tid & 3;
            const float* cr = ws + WS_CTX + j * D + p * 128;
            const float* mr = ws + WS_M + h * D + p * 128;
            float s = 0.f;
#pragma unroll 8
            for (int c4 = 0; c4 < 32; ++c4) {
                float4 a = *(const float4*)(cr + c4 * 4);
                float4 b = *(const float4*)(mr + c4 * 4);
                s += a.x*b.x + a.y*b.y + a.z*b.z + a.w*b.w;
            }
            s += __shfl_xor(s, 1);
            s += __shfl_xor(s, 2);
            if (p == 0) s_lds[j] = (s + ws[WS_T + h]) * 0.125f;
        }
        __syncthreads();
        if (wib == 0) {
            float sc = s_lds[lane];
            float mx = sc;
#pragma unroll
            for (int off = 32; off > 0; off >>= 1) mx = fmaxf(mx, __shfl_xor(mx, off));
            float e = __expf(sc - mx);
            float sum = waveReduceSum(e);
            w_lds[lane] = e / sum;
        }
        __syncthreads();
        for (int c = tid; c < D; c += 256) {
            float acc = 0.f;
#pragma unroll 8
            for (int j = 0; j < CCTX; ++j) acc += w_lds[j] * ws[WS_CTX + j * D + c];
            ws[WS_CBAR + h * D + c] = acc;
        }
    }
    barFlags(flags, 2);

    // ---- P2: o = Wv @ cbar + bv (per-head x) ----
    matvec_rows(Win1 + 2 * (size_t)D * D, ws + WS_CBAR, bin1 + 2 * D, ws + WS_O, D);
    barFlags(flags, 3);

    // ---- P3: out1 = Wout1 @ o + bout1 ----
    matvec_rows(Wout1, ws + WS_O, bout1, ws + WS_OUT1, 0);
    barFlags(flags, 4);

    // ---- P4: xs = LN(out1 + path)*g1+b1, v = Wv2 @ xs + bv2 ----
    {
        float* xs  = smem;          // 512
        float* red = smem + 520;    // 8
        float a0 = ws[WS_OUT1 + tid * 2]     + path[tid * 2];
        float a1 = ws[WS_OUT1 + tid * 2 + 1] + path[tid * 2 + 1];
        float s  = a0 + a1;
        float s2 = a0 * a0 + a1 * a1;
        s  = waveReduceSum(s);
        s2 = waveReduceSum(s2);
        if (lane == 0) { red[wib] = s; red[4 + wib] = s2; }
        __syncthreads();
        float st  = red[0] + red[1] + red[2] + red[3];
        float s2t = red[4] + red[5] + red[6] + red[7];
        float mu   = st * (1.f / D);
        float var  = s2t * (1.f / D) - mu * mu;
        float rinv = rsqrtf(var + LN_EPS);
        xs[tid * 2]     = (a0 - mu) * rinv * ln1g[tid * 2]     + ln1b[tid * 2];
        xs[tid * 2 + 1] = (a1 - mu) * rinv * ln1g[tid * 2 + 1] + ln1b[tid * 2 + 1];
        __syncthreads();
        matvec_rows(Win2 + 2 * (size_t)D * D, xs, bin2 + 2 * D, ws + WS_V, 0);
    }
    barFlags(flags, 5);

    // ---- P5: attn2 = Wout2 @ v + bout2 ----
    matvec_rows(Wout2, ws + WS_V, bout2, ws + WS_ATTN2, 0);
}

// H_cond[i,:] = LN(attn2 + H[i,:]) * g + b — GLOBAL PHASE-SEPARATED:
// 768 persistent blocks (exactly 3/CU, co-resident) iterate 6 rounds of
// {read-burst H->LDS + in-LDS reduce | grid barrier | transform + NT-write
// burst | grid barrier}. At any instant the entire GPU is either a pure
// read stream or a pure write stream — testing whether the ~2.5 TB/s mixed
// rate is a concurrency artifact (pure read 6.3 + pure write 7.2 would give
// ~62us of bursts + ~11 cheap barriers).
__global__ __launch_bounds__(256) void k_final(
    const float* __restrict__ Hm, const float* __restrict__ attn2,
    const float* __restrict__ g, const float* __restrict__ b,
    float* __restrict__ out, int N, int rounds, unsigned* __restrict__ f2)
{
    __shared__ __align__(16) float tile[FROWS * D];   // 51200 B
    __shared__ float murinv[FROWS * 2];
    const int tid  = threadIdx.x;
    const int lane = tid & 63, wib = tid >> 6;
    const int B = blockIdx.x;

    const f4v*   H4 = (const f4v*)Hm;
    f4v*         O4 = (f4v*)out;
    float4*      T4 = (float4*)tile;

    // per-thread fixed column data
    const int col4 = tid & 127;
    float4 av = ((const float4*)attn2)[col4];
    float4 gv = ((const float4*)g)[col4];
    float4 bv = ((const float4*)b)[col4];
    // per-lane row-reduce columns
    float4 a0 = ((const float4*)attn2)[lane];
    float4 a1 = ((const float4*)attn2)[64 + lane];

    unsigned phase = 0;
    for (int rd = 0; rd < rounds; ++rd) {
        const int rstart = (rd * NFB + B) * FROWS;
        const int nrows  = (rstart >= N) ? 0
                          : ((rstart + FROWS <= N) ? FROWS : (N - rstart));
        const int nf4 = nrows * (D / 4);
        const size_t base4 = (size_t)rstart * (D / 4);

        // ---- READ ERA: burst H -> LDS (plain loads), then in-LDS reduce ----
        if (nrows > 0) {
#pragma unroll 4
            for (int i = tid; i < nf4; i += 256) {
                f4v v = H4[base4 + i];
                float4 f; f.x = v.x; f.y = v.y; f.z = v.z; f.w = v.w;
                T4[i] = f;
            }
        }
        __syncthreads();
        if (nrows > 0) {
            for (int r = wib; r < nrows; r += 4) {
                float4 x0 = T4[r * 128 + lane];
                float4 x1 = T4[r * 128 + 64 + lane];
                float e0x = x0.x + a0.x, e0y = x0.y + a0.y, e0z = x0.z + a0.z, e0w = x0.w + a0.w;
                float e1x = x1.x + a1.x, e1y = x1.y + a1.y, e1z = x1.z + a1.z, e1w = x1.w + a1.w;
                float s  = e0x + e0y + e0z + e0w + e1x + e1y + e1z + e1w;
                float s2 = e0x*e0x + e0y*e0y + e0z*e0z + e0w*e0w
                         + e1x*e1x + e1y*e1y + e1z*e1z + e1w*e1w;
#pragma unroll
                for (int off = 32; off > 0; off >>= 1) {
                    s  += __shfl_xor(s,  off);
                    s2 += __shfl_xor(s2, off);
                }
                float mu   = s * (1.f / D);
                float var  = s2 * (1.f / D) - mu * mu;
                float rinv = rsqrtf(var + LN_EPS);
                if (lane == 0) { murinv[r * 2] = mu; murinv[r * 2 + 1] = rinv; }
            }
        }
        ++phase;
        barFinal(f2, phase);          // end of global read era

        // ---- WRITE ERA: transform + NT store burst ----
        if (nrows > 0) {
#pragma unroll 4
            for (int i = tid; i < nf4; i += 256) {
                int r = i >> 7;
                float4 x   = T4[i];
                float mu   = murinv[r * 2];
                float rinv = murinv[r * 2 + 1];
                f4v y;
                y.x = (x.x + av.x - mu) * rinv * gv.x + bv.x;
                y.y = (x.y + av.y - mu) * rinv * gv.y + bv.y;
                y.z = (x.z + av.z - mu) * rinv * gv.z + bv.z;
                y.w = (x.w + av.w - mu) * rinv * gv.w + bv.w;
                __builtin_nontemporal_store(y, O4 + base4 + i);
            }
        }
        if (rd + 1 < rounds) {
            ++phase;
            barFinal(f2, phase);      // end of global write era
        }
    }
}

extern "C" void kernel_launch(void* const* d_in, const int* in_sizes, int n_in,
                              void* d_out, int out_size, void* d_ws, size_t ws_size,
                              hipStream_t stream)
{
    const float* Hm    = (const float*)d_in[0];
    const float* path  = (const float*)d_in[1];
    const float* Win1  = (const float*)d_in[2];
    const float* bin1  = (const float*)d_in[3];
    const float* Wout1 = (const float*)d_in[4];
    const float* bout1 = (const float*)d_in[5];
    const float* Win2  = (const float*)d_in[6];
    const float* bin2  = (const float*)d_in[7];
    const float* Wout2 = (const float*)d_in[8];
    const float* bout2 = (const float*)d_in[9];
    const float* ln1g  = (const float*)d_in[10];
    const float* ln1b  = (const float*)d_in[11];
    const float* ln2g  = (const float*)d_in[12];
    const float* ln2b  = (const float*)d_in[13];
    // d_in[14] = edge_index — unused by the reference
    const int*   ids   = (const int*)d_in[15];

    float* ws  = (float*)d_ws;
    float* out = (float*)d_out;
    const int N = in_sizes[0] / D;
    const int rounds = (N + NFB * FROWS - 1) / (NFB * FROWS);   // 6 for N=100000

    k_init<<<1, 1024, 0, stream>>>((unsigned*)(ws + WS_FLAGS));
    k_chain<<<NCHAIN, 256, 0, stream>>>(Hm, path, Win1, bin1, Wout1, bout1,
                                        Win2, bin2, Wout2, bout2, ln1g, ln1b,
                                        ids, ws);
    k_final<<<NFB, 256, 0, stream>>>(Hm, ws + WS_ATTN2, ln2g, ln2b, out, N,
                                     rounds, (unsigned*)(ws + WS_FLAGS2));
}

// Round 17
// 122.982 us; speedup vs baseline: 3.0562x; 3.0562x over previous
//
#include <hip/hip_runtime.h>

#define D 512
#define NH 8
#define DH 64
#define CCTX 64
#define LN_EPS 1e-5f
#define NCHAIN 128

// workspace float offsets
#define WS_T     0        // 8
#define WS_M     512      // 4096
#define WS_CTX   5120     // 64*512
#define WS_CBAR  40960    // 4096
#define WS_O     45056    // 512
#define WS_OUT1  45568    // 512
#define WS_V     46080    // 512
#define WS_ATTN2 46592    // 512
#define WS_FLAGS 47104    // 128 unsigned (per-block barrier flags)

typedef float f4v __attribute__((ext_vector_type(4)));

__device__ __forceinline__ float waveReduceSum(float v) {
#pragma unroll
    for (int off = 32; off > 0; off >>= 1) v += __shfl_xor(v, off);
    return v;
}

// Contention-free barrier among the 128 chain blocks. RELAXED polls + one
// acquire fence on exit (r7-validated: no per-poll cache invalidation).
__device__ __forceinline__ void barFlags(unsigned* flags, unsigned phase) {
    __syncthreads();
    if (threadIdx.x == 0)
        __hip_atomic_store(&flags[blockIdx.x], phase, __ATOMIC_RELEASE,
                           __HIP_MEMORY_SCOPE_AGENT);
    if (threadIdx.x < 64) {
        while (true) {
            unsigned f0 = __hip_atomic_load(&flags[threadIdx.x],
                                            __ATOMIC_RELAXED, __HIP_MEMORY_SCOPE_AGENT);
            unsigned f1 = __hip_atomic_load(&flags[64 + threadIdx.x],
                                            __ATOMIC_RELAXED, __HIP_MEMORY_SCOPE_AGENT);
            if (__all(f0 >= phase && f1 >= phase)) break;
            __builtin_amdgcn_s_sleep(2);
        }
        __builtin_amdgcn_fence(__ATOMIC_ACQUIRE, "agent");
    }
    __syncthreads();
}

__global__ __launch_bounds__(128) void k_init(unsigned* flags) {
    flags[threadIdx.x] = 0u;
}

// wave-per-row matvec: y[r] = W[r,:] . x(+head offset) + b[r]
__device__ __forceinline__ void matvec_rows(
    const float* __restrict__ W, const float* __restrict__ x,
    const float* __restrict__ b, float* __restrict__ y, int headStride)
{
    int wib = threadIdx.x >> 6, lane = threadIdx.x & 63;
    int r = blockIdx.x * 4 + wib;                    // 0..511
    const float* xr = x + (r >> 6) * headStride;
    const float* Wr = W + (size_t)r * D;
    float4 w0 = *(const float4*)(Wr + lane * 4);
    float4 w1 = *(const float4*)(Wr + 256 + lane * 4);
    float4 x0 = *(const float4*)(xr + lane * 4);
    float4 x1 = *(const float4*)(xr + 256 + lane * 4);
    float s = w0.x*x0.x + w0.y*x0.y + w0.z*x0.z + w0.w*x0.w
            + w1.x*x1.x + w1.y*x1.y + w1.z*x1.z + w1.w*x1.w;
    s = waveReduceSum(s);
    if (lane == 0) y[r] = s + b[r];
}

// The small chain ALONE: 128 blocks x 256 threads, 5 barriers (R8 structure).
__global__ __launch_bounds__(256) void k_chain(
    const float* __restrict__ Hm,   const float* __restrict__ path,
    const float* __restrict__ Win1, const float* __restrict__ bin1,
    const float* __restrict__ Wout1,const float* __restrict__ bout1,
    const float* __restrict__ Win2, const float* __restrict__ bin2,
    const float* __restrict__ Wout2,const float* __restrict__ bout2,
    const float* __restrict__ ln1g, const float* __restrict__ ln1b,
    const int* __restrict__ ids,    float* __restrict__ ws)
{
    __shared__ __align__(16) float smem[532];
    unsigned* flags = (unsigned*)(ws + WS_FLAGS);
    const int B = blockIdx.x, tid = threadIdx.x;
    const int wib = tid >> 6, lane = tid & 63;

    // ---- P0: gather ctx (blocks 0..63) ; qh+m+t per half-head (blocks 64..79) ----
    if (B < 64) {
        if (tid < 128) {
            int id = ids[B];
            float4 v = *(const float4*)(Hm + (size_t)id * D + tid * 4);
            *(float4*)(ws + WS_CTX + B * D + tid * 4) = v;
        }
    } else if (B < 80) {
        int bm = B - 64;                 // 0..15
        int h = bm >> 1, half = bm & 1;
        float* qh_lds = smem;            // 64 floats: qh for head h
        {
            int rr = tid >> 2, p = tid & 3;
            const float* wrow = Win1 + (size_t)(h * DH + rr) * D + p * 128;
            const float* xrow = path + p * 128;
            float s = 0.f;
#pragma unroll 8
            for (int k = 0; k < 32; ++k) {
                float4 a = *(const float4*)(wrow + k * 4);
                float4 c = *(const float4*)(xrow + k * 4);
                s += a.x*c.x + a.y*c.y + a.z*c.z + a.w*c.w;
            }
            s += __shfl_xor(s, 1);
            s += __shfl_xor(s, 2);
            if (p == 0) qh_lds[rr] = s + bin1[h * DH + rr];
        }
        __syncthreads();
        {
            int c = half * 256 + tid;
            const float* Wk = Win1 + (size_t)D * D;
            float acc = 0.f;
#pragma unroll 8
            for (int d = 0; d < DH; ++d)
                acc += Wk[(size_t)(h * DH + d) * D + c] * qh_lds[d];
            ws[WS_M + h * D + c] = acc;
        }
        if (half == 0 && tid == 0) {
            float tt = 0.f;
            for (int d = 0; d < DH; ++d) tt += bin1[D + h * DH + d] * qh_lds[d];
            ws[WS_T + h] = tt;
        }
    }
    barFlags(flags, 1);

    // ---- P1: blocks 0..7 (one per head) — scores -> softmax -> cbar_h ----
    if (B < NH) {
        const int h = B;
        float* s_lds = smem;          // 64 scores
        float* w_lds = smem + 64;     // 64 weights
        {
            int j = tid >> 2, p = tid & 3;
            const float* cr = ws + WS_CTX + j * D + p * 128;
            const float* mr = ws + WS_M + h * D + p * 128;
            float s = 0.f;
#pragma unroll 8
            for (int c4 = 0; c4 < 32; ++c4) {
                float4 a = *(const float4*)(cr + c4 * 4);
                float4 b = *(const float4*)(mr + c4 * 4);
                s += a.x*b.x + a.y*b.y + a.z*b.z + a.w*b.w;
            }
            s += __shfl_xor(s, 1);
            s += __shfl_xor(s, 2);
            if (p == 0) s_lds[j] = (s + ws[WS_T + h]) * 0.125f;
        }
        __syncthreads();
        if (wib == 0) {
            float sc = s_lds[lane];
            float mx = sc;
#pragma unroll
            for (int off = 32; off > 0; off >>= 1) mx = fmaxf(mx, __shfl_xor(mx, off));
            float e = __expf(sc - mx);
            float sum = waveReduceSum(e);
            w_lds[lane] = e / sum;
        }
        __syncthreads();
        for (int c = tid; c < D; c += 256) {
            float acc = 0.f;
#pragma unroll 8
            for (int j = 0; j < CCTX; ++j) acc += w_lds[j] * ws[WS_CTX + j * D + c];
            ws[WS_CBAR + h * D + c] = acc;
        }
    }
    barFlags(flags, 2);

    // ---- P2: o = Wv @ cbar + bv (per-head x) ----
    matvec_rows(Win1 + 2 * (size_t)D * D, ws + WS_CBAR, bin1 + 2 * D, ws + WS_O, D);
    barFlags(flags, 3);

    // ---- P3: out1 = Wout1 @ o + bout1 ----
    matvec_rows(Wout1, ws + WS_O, bout1, ws + WS_OUT1, 0);
    barFlags(flags, 4);

    // ---- P4: xs = LN(out1 + path)*g1+b1, v = Wv2 @ xs + bv2 ----
    {
        float* xs  = smem;          // 512
        float* red = smem + 520;    // 8
        float a0 = ws[WS_OUT1 + tid * 2]     + path[tid * 2];
        float a1 = ws[WS_OUT1 + tid * 2 + 1] + path[tid * 2 + 1];
        float s  = a0 + a1;
        float s2 = a0 * a0 + a1 * a1;
        s  = waveReduceSum(s);
        s2 = waveReduceSum(s2);
        if (lane == 0) { red[wib] = s; red[4 + wib] = s2; }
        __syncthreads();
        float st  = red[0] + red[1] + red[2] + red[3];
        float s2t = red[4] + red[5] + red[6] + red[7];
        float mu   = st * (1.f / D);
        float var  = s2t * (1.f / D) - mu * mu;
        float rinv = rsqrtf(var + LN_EPS);
        xs[tid * 2]     = (a0 - mu) * rinv * ln1g[tid * 2]     + ln1b[tid * 2];
        xs[tid * 2 + 1] = (a1 - mu) * rinv * ln1g[tid * 2 + 1] + ln1b[tid * 2 + 1];
        __syncthreads();
        matvec_rows(Win2 + 2 * (size_t)D * D, xs, bin2 + 2 * D, ws + WS_V, 0);
    }
    barFlags(flags, 5);

    // ---- P5: attn2 = Wout2 @ v + bout2 ----
    matvec_rows(Wout2, ws + WS_V, bout2, ws + WS_ATTN2, 0);
}

// H_cond[i,:] = LN(attn2 + H[i,:]) * g + b — R3's direct final (best
// measured: 117.5us): wave per row, grid-stride, 2 float4 loads/row,
// dual shuffle reduce, NT stores.
__global__ __launch_bounds__(256) void k_final(
    const float* __restrict__ Hm, const float* __restrict__ attn2,
    const float* __restrict__ g, const float* __restrict__ b,
    float* __restrict__ out, int N)
{
    int lane = threadIdx.x & 63;
    int wib  = threadIdx.x >> 6;
    int c0 = lane * 4, c1 = 256 + lane * 4;
    float4 a0 = *(const float4*)(attn2 + c0), a1 = *(const float4*)(attn2 + c1);
    float4 g0 = *(const float4*)(g + c0),     g1 = *(const float4*)(g + c1);
    float4 b0 = *(const float4*)(b + c0),     b1 = *(const float4*)(b + c1);
    int stride = gridDim.x * 4;
    for (int row = blockIdx.x * 4 + wib; row < N; row += stride) {
        const float* hr = Hm + (size_t)row * D;
        float4 x0 = *(const float4*)(hr + c0);
        float4 x1 = *(const float4*)(hr + c1);
        x0.x += a0.x; x0.y += a0.y; x0.z += a0.z; x0.w += a0.w;
        x1.x += a1.x; x1.y += a1.y; x1.z += a1.z; x1.w += a1.w;
        float s  = x0.x + x0.y + x0.z + x0.w + x1.x + x1.y + x1.z + x1.w;
        float s2 = x0.x*x0.x + x0.y*x0.y + x0.z*x0.z + x0.w*x0.w
                 + x1.x*x1.x + x1.y*x1.y + x1.z*x1.z + x1.w*x1.w;
#pragma unroll
        for (int off = 32; off > 0; off >>= 1) {
            s  += __shfl_xor(s, off);
            s2 += __shfl_xor(s2, off);
        }
        float mu   = s * (1.f / D);
        float var  = s2 * (1.f / D) - mu * mu;
        float rinv = rsqrtf(var + LN_EPS);
        f4v y0, y1;
        y0.x = (x0.x - mu) * rinv * g0.x + b0.x;
        y0.y = (x0.y - mu) * rinv * g0.y + b0.y;
        y0.z = (x0.z - mu) * rinv * g0.z + b0.z;
        y0.w = (x0.w - mu) * rinv * g0.w + b0.w;
        y1.x = (x1.x - mu) * rinv * g1.x + b1.x;
        y1.y = (x1.y - mu) * rinv * g1.y + b1.y;
        y1.z = (x1.z - mu) * rinv * g1.z + b1.z;
        y1.w = (x1.w - mu) * rinv * g1.w + b1.w;
        float* orow = out + (size_t)row * D;
        __builtin_nontemporal_store(y0, (f4v*)(orow + c0));
        __builtin_nontemporal_store(y1, (f4v*)(orow + c1));
    }
}

extern "C" void kernel_launch(void* const* d_in, const int* in_sizes, int n_in,
                              void* d_out, int out_size, void* d_ws, size_t ws_size,
                              hipStream_t stream)
{
    const float* Hm    = (const float*)d_in[0];
    const float* path  = (const float*)d_in[1];
    const float* Win1  = (const float*)d_in[2];
    const float* bin1  = (const float*)d_in[3];
    const float* Wout1 = (const float*)d_in[4];
    const float* bout1 = (const float*)d_in[5];
    const float* Win2  = (const float*)d_in[6];
    const float* bin2  = (const float*)d_in[7];
    const float* Wout2 = (const float*)d_in[8];
    const float* bout2 = (const float*)d_in[9];
    const float* ln1g  = (const float*)d_in[10];
    const float* ln1b  = (const float*)d_in[11];
    const float* ln2g  = (const float*)d_in[12];
    const float* ln2b  = (const float*)d_in[13];
    // d_in[14] = edge_index — unused by the reference
    const int*   ids   = (const int*)d_in[15];

    float* ws  = (float*)d_ws;
    float* out = (float*)d_out;
    const int N = in_sizes[0] / D;

    k_init<<<1, 128, 0, stream>>>((unsigned*)(ws + WS_FLAGS));
    k_chain<<<NCHAIN, 256, 0, stream>>>(Hm, path, Win1, bin1, Wout1, bout1,
                                        Win2, bin2, Wout2, bout2, ln1g, ln1b,
                                        ids, ws);
    k_final<<<2048, 256, 0, stream>>>(Hm, ws + WS_ATTN2, ln2g, ln2b, out, N);
}